// Round 9
// baseline (104.201 us; speedup 1.0000x reference)
//
#include <hip/hip_runtime.h>
#include <cstdint>
#include <math.h>

namespace {

constexpr int QBLOCK = 64;
// jax: q = 0.95f * 63.0f -> f32 59.849998474121094
// high_weight = q - 59 = 0.84999847412109375 (exact), low_weight = 60 - q (exact)
constexpr float W59 = 0.15000152587890625f;  // weight for sorted[59] (5th largest)
constexpr float W60 = 0.84999847412109375f;  // weight for sorted[60] (4th largest)

// Branchless insert of v into descending top-5 list t[0]>=...>=t[4].
__device__ inline void ins5(float (&t)[5], float v) {
#pragma unroll
  for (int k = 0; k < 4; ++k) {
    float m = fmaxf(t[k], v);
    v = fminf(t[k], v);
    t[k] = m;
  }
  t[4] = fmaxf(t[4], v);
}

__device__ inline void ins4x(float (&ta)[5], float (&tb)[5], float4 u, float4 w) {
  ins5(ta, fabsf(u.x));
  ins5(tb, fabsf(w.x));
  ins5(ta, fabsf(u.y));
  ins5(tb, fabsf(w.y));
  ins5(ta, fabsf(u.z));
  ins5(tb, fabsf(w.z));
  ins5(ta, fabsf(u.w));
  ins5(tb, fabsf(w.w));
}

// 4-bit code for one element: c in 0..5 (magnitude rank), +6 if negative.
// Bit-exact to the reference: IEEE divide, then argmin-first-min tie-break
// (negative: tie -> more-negative level => '>='; positive: tie -> smaller
// level => '>').
__device__ inline unsigned code1(float xv, float s) {
  float xn = __fdiv_rn(xv, s);
  float ax = fabsf(xn);
  unsigned c;
  if (xn < 0.0f)
    c = 6u + (unsigned)(ax >= 0.375f) + (unsigned)(ax >= 0.875f) +
        (unsigned)(ax >= 1.25f) + (unsigned)(ax >= 1.75f) +
        (unsigned)(ax >= 2.5f);
  else
    c = (unsigned)(ax > 0.375f) + (unsigned)(ax > 0.875f) +
        (unsigned)(ax > 1.25f) + (unsigned)(ax > 1.75f) +
        (unsigned)(ax > 2.5f);
  return c;
}

// 16-bit packed codes for a float4.
__device__ inline unsigned code4(float4 v, float s) {
  return code1(v.x, s) | (code1(v.y, s) << 4) | (code1(v.z, s) << 8) |
         (code1(v.w, s) << 12);
}

// Pass 1: one thread per 64-element quant block. Computes the block scale
// (exact 0.95-quantile via top-5 network), the 4-bit level code of every
// element (level choice is independent of the global min/max), and per-WG
// min/max partials via plain stores. NO atomics; x is read exactly once.
__global__ __launch_bounds__(256) void scales_k(const float4* __restrict__ x4,
                                                float* __restrict__ scales,
                                                float2* __restrict__ part,
                                                uint4* __restrict__ idxp,
                                                int nblocks) {
  __shared__ float smn[256];
  __shared__ float smx[256];
  const int t = threadIdx.x;
  const int b = blockIdx.x * 256 + t;
  float sc_min = __uint_as_float(0x7F800000u);  // +inf
  float sc_max = 0.0f;
  if (b < nblocks) {
    const float4* p = x4 + (size_t)b * (QBLOCK / 4);
    float4 a0 = p[0], a1 = p[1], a2 = p[2], a3 = p[3];
    float4 a4 = p[4], a5 = p[5], a6 = p[6], a7 = p[7];
    float4 b0 = p[8], b1 = p[9], b2 = p[10], b3 = p[11];
    float4 b4 = p[12], b5 = p[13], b6 = p[14], b7 = p[15];
    // Two interleaved top-5 lists for ILP; |x| >= 0 > -1 sentinel.
    float ta[5] = {-1.f, -1.f, -1.f, -1.f, -1.f};
    float tb[5] = {-1.f, -1.f, -1.f, -1.f, -1.f};
    ins4x(ta, tb, a0, a1);
    ins4x(ta, tb, a2, a3);
    ins4x(ta, tb, a4, a5);
    ins4x(ta, tb, a6, a7);
    ins4x(ta, tb, b0, b1);
    ins4x(ta, tb, b2, b3);
    ins4x(ta, tb, b4, b5);
    ins4x(ta, tb, b6, b7);
#pragma unroll
    for (int k = 0; k < 5; ++k) ins5(ta, tb[k]);  // top-5 of the 64
    // sorted[60] = 4th largest = ta[3]; sorted[59] = 5th largest = ta[4]
    // bit-exact jax quantile: add(mul(lo,w_lo), mul(hi,w_hi)) in f32, no FMA
    float sc = __fadd_rn(__fmul_rn(ta[4], W59), __fmul_rn(ta[3], W60));
    sc = fmaxf(sc, 1e-8f);  // jnp.clip(scales, 1e-8)
    scales[b] = sc;
    sc_min = sc;
    sc_max = sc;
    // Quantize the 64 resident elements to 4-bit codes, pack 32 B per block.
    uint4 w0, w1;
    w0.x = code4(a0, sc) | (code4(a1, sc) << 16);
    w0.y = code4(a2, sc) | (code4(a3, sc) << 16);
    w0.z = code4(a4, sc) | (code4(a5, sc) << 16);
    w0.w = code4(a6, sc) | (code4(a7, sc) << 16);
    w1.x = code4(b0, sc) | (code4(b1, sc) << 16);
    w1.y = code4(b2, sc) | (code4(b3, sc) << 16);
    w1.z = code4(b4, sc) | (code4(b5, sc) << 16);
    w1.w = code4(b6, sc) | (code4(b7, sc) << 16);
    idxp[(size_t)b * 2] = w0;
    idxp[(size_t)b * 2 + 1] = w1;
  }
  smn[t] = sc_min;
  smx[t] = sc_max;
  __syncthreads();
  if (t < 64) {
    float mn = fminf(fminf(smn[t], smn[t + 64]), fminf(smn[t + 128], smn[t + 192]));
    float mx = fmaxf(fmaxf(smx[t], smx[t + 64]), fmaxf(smx[t + 128], smx[t + 192]));
#pragma unroll
    for (int off = 32; off; off >>= 1) {
      mn = fminf(mn, __shfl_xor(mn, off));
      mx = fmaxf(mx, __shfl_xor(mx, off));
    }
    if (t == 0) part[blockIdx.x] = make_float2(mn, mx);
  }
}

// Decode one 4-bit code -> level * dq (bit-exact final multiply).
__device__ inline float dec1(unsigned code, float dq) {
  unsigned m = (code >= 6u) ? code - 6u : code;
  float mag = (m == 0u) ? 0.0f
            : (m == 1u) ? 0.75f
            : (m == 2u) ? 1.0f
            : (m == 3u) ? 1.5f
            : (m == 4u) ? 2.0f
                        : 3.0f;
  float lvl = (code >= 6u) ? -mag : mag;
  return __fmul_rn(lvl, dq);
}

__device__ inline float4 dec8_lo(unsigned w, float dq) {
  float4 r;
  r.x = dec1(w & 15u, dq);
  r.y = dec1((w >> 4) & 15u, dq);
  r.z = dec1((w >> 8) & 15u, dq);
  r.w = dec1((w >> 12) & 15u, dq);
  return r;
}

// Pass 2: one thread per quant block. Reduces the nwg partials per-WG
// (L2-resident, no atomics), computes the double-quantized dq per block, and
// writes out = level * dq directly (differs from the x+(xq-x) STE chain by
// <= ~1 ulp). x is NOT re-read.
__global__ __launch_bounds__(256) void deq_k(const uint4* __restrict__ idxp,
                                             const float* __restrict__ scales,
                                             const float2* __restrict__ part,
                                             float4* __restrict__ o4,
                                             int nblocks, int nwg) {
  __shared__ float smn[256];
  __shared__ float smx[256];
  __shared__ float bc[2];
  const int t = threadIdx.x;
  float mn = __uint_as_float(0x7F800000u);
  float mx = 0.0f;
  for (int i = t; i < nwg; i += 256) {
    float2 pr = part[i];
    mn = fminf(mn, pr.x);
    mx = fmaxf(mx, pr.y);
  }
  smn[t] = mn;
  smx[t] = mx;
  __syncthreads();
  if (t < 64) {
    float mn2 = fminf(fminf(smn[t], smn[t + 64]), fminf(smn[t + 128], smn[t + 192]));
    float mx2 = fmaxf(fmaxf(smx[t], smx[t + 64]), fmaxf(smx[t + 128], smx[t + 192]));
#pragma unroll
    for (int off = 32; off; off >>= 1) {
      mn2 = fminf(mn2, __shfl_xor(mn2, off));
      mx2 = fmaxf(mx2, __shfl_xor(mx2, off));
    }
    if (t == 0) {
      bc[0] = mn2;
      bc[1] = mx2;
    }
  }
  __syncthreads();
  const float smin = bc[0];
  const float smax = bc[1];
  const bool nd = smax > smin;
  const float ss = nd ? __fdiv_rn(__fsub_rn(smax, smin), 255.0f) : 1.0f;

  const int b = blockIdx.x * 256 + t;
  if (b < nblocks) {
    float s = scales[b];
    float dq = 0.0f;
    if (nd) {
      float q = rintf(__fdiv_rn(__fsub_rn(s, smin), ss));  // jnp.round = RNE
      q = fminf(fmaxf(q, 0.0f), 255.0f);
      dq = __fmul_rn(q, ss);  // q_scales * scale_scale (no s_min added back)
    }
    uint4 w0 = idxp[(size_t)b * 2];
    uint4 w1 = idxp[(size_t)b * 2 + 1];
    float4* q4 = o4 + (size_t)b * (QBLOCK / 4);
    q4[0] = dec8_lo(w0.x, dq);
    q4[1] = dec8_lo(w0.x >> 16, dq);
    q4[2] = dec8_lo(w0.y, dq);
    q4[3] = dec8_lo(w0.y >> 16, dq);
    q4[4] = dec8_lo(w0.z, dq);
    q4[5] = dec8_lo(w0.z >> 16, dq);
    q4[6] = dec8_lo(w0.w, dq);
    q4[7] = dec8_lo(w0.w >> 16, dq);
    q4[8] = dec8_lo(w1.x, dq);
    q4[9] = dec8_lo(w1.x >> 16, dq);
    q4[10] = dec8_lo(w1.y, dq);
    q4[11] = dec8_lo(w1.y >> 16, dq);
    q4[12] = dec8_lo(w1.z, dq);
    q4[13] = dec8_lo(w1.z >> 16, dq);
    q4[14] = dec8_lo(w1.w, dq);
    q4[15] = dec8_lo(w1.w >> 16, dq);
  }
}

}  // namespace

extern "C" void kernel_launch(void* const* d_in, const int* in_sizes, int n_in,
                              void* d_out, int out_size, void* d_ws, size_t ws_size,
                              hipStream_t stream) {
  const float* x = (const float*)d_in[0];
  float* out = (float*)d_out;
  const int n = in_sizes[0];
  const int nblocks = n / QBLOCK;
  const int nwg = (nblocks + 255) / 256;  // 1024 for 2048x8192

  // ws layout (16-B aligned): packed codes | scales | partials
  uint4* idxp = (uint4*)d_ws;                                  // 32 B / block
  float* scales = (float*)((char*)d_ws + (size_t)nblocks * 32);  // 4 B / block
  float2* part = (float2*)((char*)scales + (size_t)nblocks * 4);

  hipLaunchKernelGGL(scales_k, dim3(nwg), dim3(256), 0, stream,
                     (const float4*)x, scales, part, idxp, nblocks);
  hipLaunchKernelGGL(deq_k, dim3(nwg), dim3(256), 0, stream, idxp, scales,
                     part, (float4*)out, nblocks, nwg);
}

// Round 10
// 59.423 us; speedup vs baseline: 1.7536x; 1.7536x over previous
//
#include <hip/hip_runtime.h>
#include <cstdint>
#include <math.h>

namespace {

constexpr int QBLOCK = 64;
// jax: q = 0.95f * 63.0f -> f32 59.849998474121094
// high_weight = q - 59 = 0.84999847412109375 (exact), low_weight = 60 - q (exact)
constexpr float W59 = 0.15000152587890625f;  // weight for sorted[59] (5th largest)
constexpr float W60 = 0.84999847412109375f;  // weight for sorted[60] (4th largest)

// Branchless insert of v into descending top-5 list t[0]>=...>=t[4].
__device__ inline void ins5(float (&t)[5], float v) {
#pragma unroll
  for (int k = 0; k < 4; ++k) {
    float m = fmaxf(t[k], v);
    v = fminf(t[k], v);
    t[k] = m;
  }
  t[4] = fmaxf(t[4], v);
}

__device__ inline void ins4x(float (&ta)[5], float (&tb)[5], float4 u, float4 w) {
  ins5(ta, fabsf(u.x));
  ins5(tb, fabsf(w.x));
  ins5(ta, fabsf(u.y));
  ins5(tb, fabsf(w.y));
  ins5(ta, fabsf(u.z));
  ins5(tb, fabsf(w.z));
  ins5(ta, fabsf(u.w));
  ins5(tb, fabsf(w.w));
}

// 4-bit code for one element: c in 0..5 (magnitude rank), +6 if negative.
// Bit-exact to the reference: IEEE divide, then argmin-first-min tie-break
// (negative: tie -> more-negative level => '>='; positive: tie -> smaller
// level => '>').
__device__ inline unsigned code1(float xv, float s) {
  float xn = __fdiv_rn(xv, s);
  float ax = fabsf(xn);
  unsigned c;
  if (xn < 0.0f)
    c = 6u + (unsigned)(ax >= 0.375f) + (unsigned)(ax >= 0.875f) +
        (unsigned)(ax >= 1.25f) + (unsigned)(ax >= 1.75f) +
        (unsigned)(ax >= 2.5f);
  else
    c = (unsigned)(ax > 0.375f) + (unsigned)(ax > 0.875f) +
        (unsigned)(ax > 1.25f) + (unsigned)(ax > 1.75f) +
        (unsigned)(ax > 2.5f);
  return c;
}

// 16-bit packed codes for a float4.
__device__ inline unsigned code4(float4 v, float s) {
  return code1(v.x, s) | (code1(v.y, s) << 4) | (code1(v.z, s) << 8) |
         (code1(v.w, s) << 12);
}

// Pass 1: one thread per 64-element quant block. Computes the block scale
// (exact 0.95-quantile via top-5 network), the 4-bit level code of every
// element (level choice is independent of the global min/max), and per-WG
// min/max partials via plain stores. NO atomics; x is read exactly once.
__global__ __launch_bounds__(256) void scales_k(const float4* __restrict__ x4,
                                                float* __restrict__ scales,
                                                float2* __restrict__ part,
                                                uint4* __restrict__ idxp,
                                                int nblocks) {
  __shared__ float smn[256];
  __shared__ float smx[256];
  const int t = threadIdx.x;
  const int b = blockIdx.x * 256 + t;
  float sc_min = __uint_as_float(0x7F800000u);  // +inf
  float sc_max = 0.0f;
  if (b < nblocks) {
    const float4* p = x4 + (size_t)b * (QBLOCK / 4);
    float4 a0 = p[0], a1 = p[1], a2 = p[2], a3 = p[3];
    float4 a4 = p[4], a5 = p[5], a6 = p[6], a7 = p[7];
    float4 b0 = p[8], b1 = p[9], b2 = p[10], b3 = p[11];
    float4 b4 = p[12], b5 = p[13], b6 = p[14], b7 = p[15];
    // Two interleaved top-5 lists for ILP; |x| >= 0 > -1 sentinel.
    float ta[5] = {-1.f, -1.f, -1.f, -1.f, -1.f};
    float tb[5] = {-1.f, -1.f, -1.f, -1.f, -1.f};
    ins4x(ta, tb, a0, a1);
    ins4x(ta, tb, a2, a3);
    ins4x(ta, tb, a4, a5);
    ins4x(ta, tb, a6, a7);
    ins4x(ta, tb, b0, b1);
    ins4x(ta, tb, b2, b3);
    ins4x(ta, tb, b4, b5);
    ins4x(ta, tb, b6, b7);
#pragma unroll
    for (int k = 0; k < 5; ++k) ins5(ta, tb[k]);  // top-5 of the 64
    // sorted[60] = 4th largest = ta[3]; sorted[59] = 5th largest = ta[4]
    // bit-exact jax quantile: add(mul(lo,w_lo), mul(hi,w_hi)) in f32, no FMA
    float sc = __fadd_rn(__fmul_rn(ta[4], W59), __fmul_rn(ta[3], W60));
    sc = fmaxf(sc, 1e-8f);  // jnp.clip(scales, 1e-8)
    scales[b] = sc;
    sc_min = sc;
    sc_max = sc;
    // Quantize the 64 resident elements to 4-bit codes, pack 32 B per block.
    // ushort k of block b (byte b*32+2k) = codes of output float4 (b*16+k).
    uint4 w0, w1;
    w0.x = code4(a0, sc) | (code4(a1, sc) << 16);
    w0.y = code4(a2, sc) | (code4(a3, sc) << 16);
    w0.z = code4(a4, sc) | (code4(a5, sc) << 16);
    w0.w = code4(a6, sc) | (code4(a7, sc) << 16);
    w1.x = code4(b0, sc) | (code4(b1, sc) << 16);
    w1.y = code4(b2, sc) | (code4(b3, sc) << 16);
    w1.z = code4(b4, sc) | (code4(b5, sc) << 16);
    w1.w = code4(b6, sc) | (code4(b7, sc) << 16);
    idxp[(size_t)b * 2] = w0;
    idxp[(size_t)b * 2 + 1] = w1;
  }
  smn[t] = sc_min;
  smx[t] = sc_max;
  __syncthreads();
  if (t < 64) {
    float mn = fminf(fminf(smn[t], smn[t + 64]), fminf(smn[t + 128], smn[t + 192]));
    float mx = fmaxf(fmaxf(smx[t], smx[t + 64]), fmaxf(smx[t + 128], smx[t + 192]));
#pragma unroll
    for (int off = 32; off; off >>= 1) {
      mn = fminf(mn, __shfl_xor(mn, off));
      mx = fmaxf(mx, __shfl_xor(mx, off));
    }
    if (t == 0) part[blockIdx.x] = make_float2(mn, mx);
  }
}

// Decode one 4-bit code -> level * dq (bit-exact final multiply).
__device__ inline float dec1(unsigned code, float dq) {
  unsigned m = (code >= 6u) ? code - 6u : code;
  float mag = (m == 0u) ? 0.0f
            : (m == 1u) ? 0.75f
            : (m == 2u) ? 1.0f
            : (m == 3u) ? 1.5f
            : (m == 4u) ? 2.0f
                        : 3.0f;
  float lvl = (code >= 6u) ? -mag : mag;
  return __fmul_rn(lvl, dq);
}

// Pass 2: thread <-> output float4 index (grid-stride) => coalesced 2-B code
// loads and 16-B stores (round 9's per-thread 256-B store range caused 4.3x
// write amplification: WRITE_SIZE 291 MB for a 67 MB output).
__global__ __launch_bounds__(256) void deq_k(const ushort* __restrict__ codes,
                                             const float* __restrict__ scales,
                                             const float2* __restrict__ part,
                                             float4* __restrict__ o4, int n4,
                                             int nwg) {
  __shared__ float smn[256];
  __shared__ float smx[256];
  __shared__ float bc[2];
  const int t = threadIdx.x;
  float mn = __uint_as_float(0x7F800000u);
  float mx = 0.0f;
  for (int i = t; i < nwg; i += 256) {
    float2 pr = part[i];
    mn = fminf(mn, pr.x);
    mx = fmaxf(mx, pr.y);
  }
  smn[t] = mn;
  smx[t] = mx;
  __syncthreads();
  if (t < 64) {
    float mn2 = fminf(fminf(smn[t], smn[t + 64]), fminf(smn[t + 128], smn[t + 192]));
    float mx2 = fmaxf(fmaxf(smx[t], smx[t + 64]), fmaxf(smx[t + 128], smx[t + 192]));
#pragma unroll
    for (int off = 32; off; off >>= 1) {
      mn2 = fminf(mn2, __shfl_xor(mn2, off));
      mx2 = fmaxf(mx2, __shfl_xor(mx2, off));
    }
    if (t == 0) {
      bc[0] = mn2;
      bc[1] = mx2;
    }
  }
  __syncthreads();
  const float smin = bc[0];
  const float smax = bc[1];
  const bool nd = smax > smin;
  const float ss = nd ? __fdiv_rn(__fsub_rn(smax, smin), 255.0f) : 1.0f;

  int i = blockIdx.x * 256 + t;
  const int stride = gridDim.x * 256;
  for (; i < n4; i += stride) {
    unsigned w = codes[i];
    float s = scales[i >> 4];
    float dq = 0.0f;
    if (nd) {
      float q = rintf(__fdiv_rn(__fsub_rn(s, smin), ss));  // jnp.round = RNE
      q = fminf(fmaxf(q, 0.0f), 255.0f);
      dq = __fmul_rn(q, ss);  // q_scales * scale_scale (no s_min added back)
    }
    float4 o;
    o.x = dec1(w & 15u, dq);
    o.y = dec1((w >> 4) & 15u, dq);
    o.z = dec1((w >> 8) & 15u, dq);
    o.w = dec1((w >> 12) & 15u, dq);
    o4[i] = o;
  }
}

}  // namespace

extern "C" void kernel_launch(void* const* d_in, const int* in_sizes, int n_in,
                              void* d_out, int out_size, void* d_ws, size_t ws_size,
                              hipStream_t stream) {
  const float* x = (const float*)d_in[0];
  float* out = (float*)d_out;
  const int n = in_sizes[0];
  const int nblocks = n / QBLOCK;
  const int nwg = (nblocks + 255) / 256;  // 1024 for 2048x8192

  // ws layout (16-B aligned): packed codes | scales | partials
  uint4* idxp = (uint4*)d_ws;                                    // 32 B / block
  float* scales = (float*)((char*)d_ws + (size_t)nblocks * 32);  // 4 B / block
  float2* part = (float2*)((char*)scales + (size_t)nblocks * 4);

  hipLaunchKernelGGL(scales_k, dim3(nwg), dim3(256), 0, stream,
                     (const float4*)x, scales, part, idxp, nblocks);
  const int n4 = n / 4;
  hipLaunchKernelGGL(deq_k, dim3(2048), dim3(256), 0, stream,
                     (const ushort*)d_ws, scales, part, (float4*)out, n4, nwg);
}

// Round 11
// 56.019 us; speedup vs baseline: 1.8601x; 1.0608x over previous
//
#include <hip/hip_runtime.h>
#include <cstdint>
#include <math.h>

namespace {

constexpr int QBLOCK = 64;
// jax: q = 0.95f * 63.0f -> f32 59.849998474121094
// high_weight = q - 59 = 0.84999847412109375 (exact), low_weight = 60 - q (exact)
constexpr float W59 = 0.15000152587890625f;  // weight for sorted[59] (5th largest)
constexpr float W60 = 0.84999847412109375f;  // weight for sorted[60] (4th largest)

// Branchless insert of v into descending top-5 list t[0]>=...>=t[4].
__device__ inline void ins5(float (&t)[5], float v) {
#pragma unroll
  for (int k = 0; k < 4; ++k) {
    float m = fmaxf(t[k], v);
    v = fminf(t[k], v);
    t[k] = m;
  }
  t[4] = fmaxf(t[4], v);
}

// 4-bit code for one element: c in 0..5 (magnitude rank), +6 if negative.
// Bit-exact: IEEE divide, then argmin-first-min tie-break (negative: tie ->
// more-negative level => '>='; positive: tie -> smaller level => '>').
__device__ inline unsigned code1(float xv, float s) {
  float xn = __fdiv_rn(xv, s);
  float ax = fabsf(xn);
  unsigned c;
  if (xn < 0.0f)
    c = 6u + (unsigned)(ax >= 0.375f) + (unsigned)(ax >= 0.875f) +
        (unsigned)(ax >= 1.25f) + (unsigned)(ax >= 1.75f) +
        (unsigned)(ax >= 2.5f);
  else
    c = (unsigned)(ax > 0.375f) + (unsigned)(ax > 0.875f) +
        (unsigned)(ax > 1.25f) + (unsigned)(ax > 1.75f) +
        (unsigned)(ax > 2.5f);
  return c;
}

// 16-bit packed codes for a float4.
__device__ inline unsigned code4(float4 v, float s) {
  return code1(v.x, s) | (code1(v.y, s) << 4) | (code1(v.z, s) << 8) |
         (code1(v.w, s) << 12);
}

// Pass 1: FOUR lanes per 64-element quant block (sub = tid&3), interleaved
// loads x4[b*16 + sub + 4j] so each wave-load fetches 16 fully-consumed 64-B
// lines. Exact top-5 via per-lane network + 2-round shfl_xor merge. Codes
// repacked through LDS so the global code store is linear/coalesced.
// NO atomics anywhere.
__global__ __launch_bounds__(256) void scales_k(const float4* __restrict__ x4,
                                                float* __restrict__ scales,
                                                float2* __restrict__ part,
                                                uint2* __restrict__ codes8,
                                                int nblocks) {
  __shared__ uint lcode[512];  // 64 blocks * 16 ushort codes = 2 KB
  __shared__ float smn[256];
  __shared__ float smx[256];
  const int t = threadIdx.x;
  const int tid = blockIdx.x * 256 + t;
  const int b = tid >> 2;
  const int sub = tid & 3;
  float sc_min = __uint_as_float(0x7F800000u);  // +inf
  float sc_max = 0.0f;
  if (b < nblocks) {
    const float4* p = x4 + ((size_t)b << 4) + sub;
    float4 v0 = p[0];
    float4 v1 = p[4];
    float4 v2 = p[8];
    float4 v3 = p[12];
    // Two interleaved top-5 lists over my 16 elements; |x| >= 0 > -1 sentinel.
    float ta[5] = {-1.f, -1.f, -1.f, -1.f, -1.f};
    float tb[5] = {-1.f, -1.f, -1.f, -1.f, -1.f};
    ins5(ta, fabsf(v0.x));
    ins5(tb, fabsf(v2.x));
    ins5(ta, fabsf(v0.y));
    ins5(tb, fabsf(v2.y));
    ins5(ta, fabsf(v0.z));
    ins5(tb, fabsf(v2.z));
    ins5(ta, fabsf(v0.w));
    ins5(tb, fabsf(v2.w));
    ins5(ta, fabsf(v1.x));
    ins5(tb, fabsf(v3.x));
    ins5(ta, fabsf(v1.y));
    ins5(tb, fabsf(v3.y));
    ins5(ta, fabsf(v1.z));
    ins5(tb, fabsf(v3.z));
    ins5(ta, fabsf(v1.w));
    ins5(tb, fabsf(v3.w));
#pragma unroll
    for (int k = 0; k < 5; ++k) ins5(ta, tb[k]);  // top-5 of my 16
    // Butterfly merge across the block's 4 lanes (xor 1, then xor 2).
    float pb[5];
#pragma unroll
    for (int k = 0; k < 5; ++k) pb[k] = __shfl_xor(ta[k], 1);
#pragma unroll
    for (int k = 0; k < 5; ++k) ins5(ta, pb[k]);
#pragma unroll
    for (int k = 0; k < 5; ++k) pb[k] = __shfl_xor(ta[k], 2);
#pragma unroll
    for (int k = 0; k < 5; ++k) ins5(ta, pb[k]);
    // All 4 lanes now hold the block's exact top-5 (bit-identical).
    // sorted[60] = 4th largest = ta[3]; sorted[59] = 5th largest = ta[4]
    // bit-exact jax quantile: add(mul(lo,w_lo), mul(hi,w_hi)) in f32, no FMA
    float sc = __fadd_rn(__fmul_rn(ta[4], W59), __fmul_rn(ta[3], W60));
    sc = fmaxf(sc, 1e-8f);  // jnp.clip(scales, 1e-8)
    if (sub == 0) scales[b] = sc;
    sc_min = sc;
    sc_max = sc;
    // Code my 4 resident float4s; slots (t>>2)*16 + sub + 4j in this WG.
    ushort* lu = (ushort*)lcode;
    const int base = (t >> 2) * 16 + sub;
    lu[base] = (ushort)code4(v0, sc);
    lu[base + 4] = (ushort)code4(v1, sc);
    lu[base + 8] = (ushort)code4(v2, sc);
    lu[base + 12] = (ushort)code4(v3, sc);
  }
  smn[t] = sc_min;
  smx[t] = sc_max;
  __syncthreads();
  // Linear readback -> coalesced 8-B global code stores.
  {
    const int u2 = blockIdx.x * 256 + t;          // uint2 index (4 ushorts)
    if (u2 * 4 < nblocks * 16) {
      uint2 w = ((const uint2*)lcode)[t];
      codes8[u2] = w;
    }
  }
  if (t < 64) {
    float mn = fminf(fminf(smn[t], smn[t + 64]), fminf(smn[t + 128], smn[t + 192]));
    float mx = fmaxf(fmaxf(smx[t], smx[t + 64]), fmaxf(smx[t + 128], smx[t + 192]));
#pragma unroll
    for (int off = 32; off; off >>= 1) {
      mn = fminf(mn, __shfl_xor(mn, off));
      mx = fmaxf(mx, __shfl_xor(mx, off));
    }
    if (t == 0) part[blockIdx.x] = make_float2(mn, mx);
  }
}

// Decode one 4-bit code -> level * dq (bit-exact final multiply).
__device__ inline float dec1(unsigned code, float dq) {
  unsigned m = (code >= 6u) ? code - 6u : code;
  float mag = (m == 0u) ? 0.0f
            : (m == 1u) ? 0.75f
            : (m == 2u) ? 1.0f
            : (m == 3u) ? 1.5f
            : (m == 4u) ? 2.0f
                        : 3.0f;
  float lvl = (code >= 6u) ? -mag : mag;
  return __fmul_rn(lvl, dq);
}

// Pass 2: thread <-> output float4 index (grid-stride) => coalesced 2-B code
// loads and 16-B stores.
__global__ __launch_bounds__(256) void deq_k(const ushort* __restrict__ codes,
                                             const float* __restrict__ scales,
                                             const float2* __restrict__ part,
                                             float4* __restrict__ o4, int n4,
                                             int nwg) {
  __shared__ float smn[256];
  __shared__ float smx[256];
  __shared__ float bc[2];
  const int t = threadIdx.x;
  float mn = __uint_as_float(0x7F800000u);
  float mx = 0.0f;
  for (int i = t; i < nwg; i += 256) {
    float2 pr = part[i];
    mn = fminf(mn, pr.x);
    mx = fmaxf(mx, pr.y);
  }
  smn[t] = mn;
  smx[t] = mx;
  __syncthreads();
  if (t < 64) {
    float mn2 = fminf(fminf(smn[t], smn[t + 64]), fminf(smn[t + 128], smn[t + 192]));
    float mx2 = fmaxf(fmaxf(smx[t], smx[t + 64]), fmaxf(smx[t + 128], smx[t + 192]));
#pragma unroll
    for (int off = 32; off; off >>= 1) {
      mn2 = fminf(mn2, __shfl_xor(mn2, off));
      mx2 = fmaxf(mx2, __shfl_xor(mx2, off));
    }
    if (t == 0) {
      bc[0] = mn2;
      bc[1] = mx2;
    }
  }
  __syncthreads();
  const float smin = bc[0];
  const float smax = bc[1];
  const bool nd = smax > smin;
  const float ss = nd ? __fdiv_rn(__fsub_rn(smax, smin), 255.0f) : 1.0f;

  int i = blockIdx.x * 256 + t;
  const int stride = gridDim.x * 256;
  for (; i < n4; i += stride) {
    unsigned w = codes[i];
    float s = scales[i >> 4];
    float dq = 0.0f;
    if (nd) {
      float q = rintf(__fdiv_rn(__fsub_rn(s, smin), ss));  // jnp.round = RNE
      q = fminf(fmaxf(q, 0.0f), 255.0f);
      dq = __fmul_rn(q, ss);  // q_scales * scale_scale (no s_min added back)
    }
    float4 o;
    o.x = dec1(w & 15u, dq);
    o.y = dec1((w >> 4) & 15u, dq);
    o.z = dec1((w >> 8) & 15u, dq);
    o.w = dec1((w >> 12) & 15u, dq);
    o4[i] = o;
  }
}

}  // namespace

extern "C" void kernel_launch(void* const* d_in, const int* in_sizes, int n_in,
                              void* d_out, int out_size, void* d_ws, size_t ws_size,
                              hipStream_t stream) {
  const float* x = (const float*)d_in[0];
  float* out = (float*)d_out;
  const int n = in_sizes[0];
  const int nblocks = n / QBLOCK;

  // ws layout (16-B aligned): packed codes | scales | partials
  uint2* codes8 = (uint2*)d_ws;                                  // 32 B / block
  float* scales = (float*)((char*)d_ws + (size_t)nblocks * 32);  // 4 B / block
  float2* part = (float2*)((char*)scales + (size_t)nblocks * 4);

  const long long nthreads = (long long)nblocks * 4;  // 4 lanes per block
  const int nwg1 = (int)((nthreads + 255) / 256);     // 4096 for 2048x8192
  hipLaunchKernelGGL(scales_k, dim3(nwg1), dim3(256), 0, stream,
                     (const float4*)x, scales, part, codes8, nblocks);
  const int n4 = n / 4;
  hipLaunchKernelGGL(deq_k, dim3(2048), dim3(256), 0, stream,
                     (const ushort*)d_ws, scales, part, (float4*)out, n4, nwg1);
}

// Round 12
// 54.497 us; speedup vs baseline: 1.9120x; 1.0279x over previous
//
#include <hip/hip_runtime.h>
#include <cstdint>
#include <math.h>

namespace {

constexpr int QBLOCK = 64;
// jax: q = 0.95f * 63.0f -> f32 59.849998474121094
// high_weight = q - 59 = 0.84999847412109375 (exact), low_weight = 60 - q (exact)
constexpr float W59 = 0.15000152587890625f;  // weight for sorted[59] (5th largest)
constexpr float W60 = 0.84999847412109375f;  // weight for sorted[60] (4th largest)

// Midpoints between adjacent FP4 magnitude levels {0,0.75,1,1.5,2,3}, shifted
// by the f32 half-ulp at each midpoint (binade-dependent):
//   fl(q) >  m  <=>  q >  m + d   (positive-x tie-break: strict)
//   fl(q) >= m  <=>  q >= m - d   (negative-x tie-break: inclusive)
// (all five m have even mantissas, so RNE midpoint ties round to m).
constexpr double MP0 = 0.375 + 0x1p-26, MN0 = 0.375 - 0x1p-26;
constexpr double MP1 = 0.875 + 0x1p-25, MN1 = 0.875 - 0x1p-25;
constexpr double MP2 = 1.25 + 0x1p-24, MN2 = 1.25 - 0x1p-24;
constexpr double MP3 = 1.75 + 0x1p-24, MN3 = 1.75 - 0x1p-24;
constexpr double MP4 = 2.5 + 0x1p-23, MN4 = 2.5 - 0x1p-23;

// Smallest f32 >= sd*md. sd*md is exact in f64 (24-bit * 25-bit mantissas),
// and is never exactly an f32 (odd 25-bit factor), so comparing |x| >= thr()
// reproduces fl(|x|/s) vs m bit-exactly, with the right tie direction baked
// into md. Replaces the per-element IEEE divide (7-deep dependent chain with
// a quarter-rate v_rcp) by one full-rate f32 compare.
__device__ inline float thr(double sd, double md) {
  double t = sd * md;  // exact
  float t32 = (float)t;
  return ((double)t32 < t) ? __uint_as_float(__float_as_uint(t32) + 1u) : t32;
}

// Branchless insert of v into descending top-5 list t[0]>=...>=t[4].
__device__ inline void ins5(float (&t)[5], float v) {
#pragma unroll
  for (int k = 0; k < 4; ++k) {
    float m = fmaxf(t[k], v);
    v = fminf(t[k], v);
    t[k] = m;
  }
  t[4] = fmaxf(t[4], v);
}

// 4-bit code via threshold compares: c in 0..5 (magnitude rank), +6 if neg.
__device__ inline unsigned code1t(float xv, const float (&tp)[5],
                                  const float (&tn)[5]) {
  const bool neg = xv < 0.0f;
  const float ax = fabsf(xv);
  unsigned c = neg ? 6u : 0u;
#pragma unroll
  for (int k = 0; k < 5; ++k) {
    float t = neg ? tn[k] : tp[k];
    c += (unsigned)(ax >= t);
  }
  return c;
}

__device__ inline unsigned code4t(float4 v, const float (&tp)[5],
                                  const float (&tn)[5]) {
  return code1t(v.x, tp, tn) | (code1t(v.y, tp, tn) << 4) |
         (code1t(v.z, tp, tn) << 8) | (code1t(v.w, tp, tn) << 12);
}

// Pass 1: FOUR lanes per 64-element quant block (sub = tid&3), interleaved
// loads x4[b*16 + sub + 4j]. Exact top-5 via per-lane network + 2-round
// shfl_xor merge. Codes via divide-free threshold compares, repacked through
// LDS for coalesced global stores. NO atomics anywhere.
__global__ __launch_bounds__(256) void scales_k(const float4* __restrict__ x4,
                                                float* __restrict__ scales,
                                                float2* __restrict__ part,
                                                uint2* __restrict__ codes8,
                                                int nblocks) {
  __shared__ uint lcode[512];  // 64 blocks * 16 ushort codes = 2 KB
  __shared__ float smn[256];
  __shared__ float smx[256];
  const int t = threadIdx.x;
  const int tid = blockIdx.x * 256 + t;
  const int b = tid >> 2;
  const int sub = tid & 3;
  float sc_min = __uint_as_float(0x7F800000u);  // +inf
  float sc_max = 0.0f;
  if (b < nblocks) {
    const float4* p = x4 + ((size_t)b << 4) + sub;
    float4 v0 = p[0];
    float4 v1 = p[4];
    float4 v2 = p[8];
    float4 v3 = p[12];
    // Two interleaved top-5 lists over my 16 elements; |x| >= 0 > -1 sentinel.
    float ta[5] = {-1.f, -1.f, -1.f, -1.f, -1.f};
    float tb[5] = {-1.f, -1.f, -1.f, -1.f, -1.f};
    ins5(ta, fabsf(v0.x));
    ins5(tb, fabsf(v2.x));
    ins5(ta, fabsf(v0.y));
    ins5(tb, fabsf(v2.y));
    ins5(ta, fabsf(v0.z));
    ins5(tb, fabsf(v2.z));
    ins5(ta, fabsf(v0.w));
    ins5(tb, fabsf(v2.w));
    ins5(ta, fabsf(v1.x));
    ins5(tb, fabsf(v3.x));
    ins5(ta, fabsf(v1.y));
    ins5(tb, fabsf(v3.y));
    ins5(ta, fabsf(v1.z));
    ins5(tb, fabsf(v3.z));
    ins5(ta, fabsf(v1.w));
    ins5(tb, fabsf(v3.w));
#pragma unroll
    for (int k = 0; k < 5; ++k) ins5(ta, tb[k]);  // top-5 of my 16
    // Butterfly merge across the block's 4 lanes (xor 1, then xor 2).
    float pb[5];
#pragma unroll
    for (int k = 0; k < 5; ++k) pb[k] = __shfl_xor(ta[k], 1);
#pragma unroll
    for (int k = 0; k < 5; ++k) ins5(ta, pb[k]);
#pragma unroll
    for (int k = 0; k < 5; ++k) pb[k] = __shfl_xor(ta[k], 2);
#pragma unroll
    for (int k = 0; k < 5; ++k) ins5(ta, pb[k]);
    // All 4 lanes now hold the block's exact top-5 (bit-identical).
    // sorted[60] = 4th largest = ta[3]; sorted[59] = 5th largest = ta[4]
    // bit-exact jax quantile: add(mul(lo,w_lo), mul(hi,w_hi)) in f32, no FMA
    float sc = __fadd_rn(__fmul_rn(ta[4], W59), __fmul_rn(ta[3], W60));
    sc = fmaxf(sc, 1e-8f);  // jnp.clip(scales, 1e-8)
    if (sub == 0) scales[b] = sc;
    sc_min = sc;
    sc_max = sc;
    // Per-block divide-free thresholds (exact; see thr()).
    const double sd = (double)sc;
    float tp[5], tn[5];
    tp[0] = thr(sd, MP0);
    tn[0] = thr(sd, MN0);
    tp[1] = thr(sd, MP1);
    tn[1] = thr(sd, MN1);
    tp[2] = thr(sd, MP2);
    tn[2] = thr(sd, MN2);
    tp[3] = thr(sd, MP3);
    tn[3] = thr(sd, MN3);
    tp[4] = thr(sd, MP4);
    tn[4] = thr(sd, MN4);
    // Code my 4 resident float4s; slots (t>>2)*16 + sub + 4j in this WG.
    ushort* lu = (ushort*)lcode;
    const int base = (t >> 2) * 16 + sub;
    lu[base] = (ushort)code4t(v0, tp, tn);
    lu[base + 4] = (ushort)code4t(v1, tp, tn);
    lu[base + 8] = (ushort)code4t(v2, tp, tn);
    lu[base + 12] = (ushort)code4t(v3, tp, tn);
  }
  smn[t] = sc_min;
  smx[t] = sc_max;
  __syncthreads();
  // Linear readback -> coalesced 8-B global code stores.
  {
    const int u2 = blockIdx.x * 256 + t;  // uint2 index (4 ushorts)
    if (u2 * 4 < nblocks * 16) {
      uint2 w = ((const uint2*)lcode)[t];
      codes8[u2] = w;
    }
  }
  if (t < 64) {
    float mn = fminf(fminf(smn[t], smn[t + 64]), fminf(smn[t + 128], smn[t + 192]));
    float mx = fmaxf(fmaxf(smx[t], smx[t + 64]), fmaxf(smx[t + 128], smx[t + 192]));
#pragma unroll
    for (int off = 32; off; off >>= 1) {
      mn = fminf(mn, __shfl_xor(mn, off));
      mx = fmaxf(mx, __shfl_xor(mx, off));
    }
    if (t == 0) part[blockIdx.x] = make_float2(mn, mx);
  }
}

// Decode one 4-bit code -> level * dq (bit-exact final multiply).
__device__ inline float dec1(unsigned code, float dq) {
  unsigned m = (code >= 6u) ? code - 6u : code;
  float mag = (m == 0u) ? 0.0f
            : (m == 1u) ? 0.75f
            : (m == 2u) ? 1.0f
            : (m == 3u) ? 1.5f
            : (m == 4u) ? 2.0f
                        : 3.0f;
  float lvl = (code >= 6u) ? -mag : mag;
  return __fmul_rn(lvl, dq);
}

// Pass 2: thread <-> output float4 index (grid-stride) => coalesced 2-B code
// loads and 16-B stores.
__global__ __launch_bounds__(256) void deq_k(const ushort* __restrict__ codes,
                                             const float* __restrict__ scales,
                                             const float2* __restrict__ part,
                                             float4* __restrict__ o4, int n4,
                                             int nwg) {
  __shared__ float smn[256];
  __shared__ float smx[256];
  __shared__ float bc[2];
  const int t = threadIdx.x;
  float mn = __uint_as_float(0x7F800000u);
  float mx = 0.0f;
  for (int i = t; i < nwg; i += 256) {
    float2 pr = part[i];
    mn = fminf(mn, pr.x);
    mx = fmaxf(mx, pr.y);
  }
  smn[t] = mn;
  smx[t] = mx;
  __syncthreads();
  if (t < 64) {
    float mn2 = fminf(fminf(smn[t], smn[t + 64]), fminf(smn[t + 128], smn[t + 192]));
    float mx2 = fmaxf(fmaxf(smx[t], smx[t + 64]), fmaxf(smx[t + 128], smx[t + 192]));
#pragma unroll
    for (int off = 32; off; off >>= 1) {
      mn2 = fminf(mn2, __shfl_xor(mn2, off));
      mx2 = fmaxf(mx2, __shfl_xor(mx2, off));
    }
    if (t == 0) {
      bc[0] = mn2;
      bc[1] = mx2;
    }
  }
  __syncthreads();
  const float smin = bc[0];
  const float smax = bc[1];
  const bool nd = smax > smin;
  const float ss = nd ? __fdiv_rn(__fsub_rn(smax, smin), 255.0f) : 1.0f;

  int i = blockIdx.x * 256 + t;
  const int stride = gridDim.x * 256;
  for (; i < n4; i += stride) {
    unsigned w = codes[i];
    float s = scales[i >> 4];
    float dq = 0.0f;
    if (nd) {
      float q = rintf(__fdiv_rn(__fsub_rn(s, smin), ss));  // jnp.round = RNE
      q = fminf(fmaxf(q, 0.0f), 255.0f);
      dq = __fmul_rn(q, ss);  // q_scales * scale_scale (no s_min added back)
    }
    float4 o;
    o.x = dec1(w & 15u, dq);
    o.y = dec1((w >> 4) & 15u, dq);
    o.z = dec1((w >> 8) & 15u, dq);
    o.w = dec1((w >> 12) & 15u, dq);
    o4[i] = o;
  }
}

}  // namespace

extern "C" void kernel_launch(void* const* d_in, const int* in_sizes, int n_in,
                              void* d_out, int out_size, void* d_ws, size_t ws_size,
                              hipStream_t stream) {
  const float* x = (const float*)d_in[0];
  float* out = (float*)d_out;
  const int n = in_sizes[0];
  const int nblocks = n / QBLOCK;

  // ws layout (16-B aligned): packed codes | scales | partials
  uint2* codes8 = (uint2*)d_ws;                                  // 32 B / block
  float* scales = (float*)((char*)d_ws + (size_t)nblocks * 32);  // 4 B / block
  float2* part = (float2*)((char*)scales + (size_t)nblocks * 4);

  const long long nthreads = (long long)nblocks * 4;  // 4 lanes per block
  const int nwg1 = (int)((nthreads + 255) / 256);     // 4096 for 2048x8192
  hipLaunchKernelGGL(scales_k, dim3(nwg1), dim3(256), 0, stream,
                     (const float4*)x, scales, part, codes8, nblocks);
  const int n4 = n / 4;
  hipLaunchKernelGGL(deq_k, dim3(2048), dim3(256), 0, stream,
                     (const ushort*)d_ws, scales, part, (float4*)out, n4, nwg1);
}

// Round 13
// 50.852 us; speedup vs baseline: 2.0491x; 1.0717x over previous
//
#include <hip/hip_runtime.h>
#include <cstdint>
#include <math.h>

namespace {

constexpr int QBLOCK = 64;
// jax: q = 0.95f * 63.0f -> f32 59.849998474121094
// high_weight = q - 59 = 0.84999847412109375 (exact), low_weight = 60 - q (exact)
constexpr float W59 = 0.15000152587890625f;  // weight for sorted[59] (5th largest)
constexpr float W60 = 0.84999847412109375f;  // weight for sorted[60] (4th largest)

// Midpoints between adjacent FP4 magnitude levels {0,0.75,1,1.5,2,3}, shifted
// by the f32 half-ulp at each midpoint (binade-dependent):
//   fl(q) >  m  <=>  q >  m + d   (positive-x tie-break: strict)
//   fl(q) >= m  <=>  q >= m - d   (negative-x tie-break: inclusive)
// (all five m have even mantissas, so RNE midpoint ties round to m).
constexpr double MP0 = 0.375 + 0x1p-26, MN0 = 0.375 - 0x1p-26;
constexpr double MP1 = 0.875 + 0x1p-25, MN1 = 0.875 - 0x1p-25;
constexpr double MP2 = 1.25 + 0x1p-24, MN2 = 1.25 - 0x1p-24;
constexpr double MP3 = 1.75 + 0x1p-24, MN3 = 1.75 - 0x1p-24;
constexpr double MP4 = 2.5 + 0x1p-23, MN4 = 2.5 - 0x1p-23;

// Smallest f32 >= sd*md. sd*md is exact in f64 (24-bit * 25-bit mantissas),
// and is never exactly an f32 (odd 25-bit factor), so comparing |x| >= thr()
// reproduces fl(|x|/s) vs m bit-exactly, with the tie direction baked into md.
__device__ inline float thr(double sd, double md) {
  double t = sd * md;  // exact
  float t32 = (float)t;
  return ((double)t32 < t) ? __uint_as_float(__float_as_uint(t32) + 1u) : t32;
}

// Branchless insert of v into descending top-5 list t[0]>=...>=t[4].
__device__ inline void ins5(float (&t)[5], float v) {
#pragma unroll
  for (int k = 0; k < 4; ++k) {
    float m = fmaxf(t[k], v);
    v = fminf(t[k], v);
    t[k] = m;
  }
  t[4] = fmaxf(t[4], v);
}

__device__ inline void ins4x(float (&ta)[5], float (&tb)[5], float4 u, float4 w) {
  ins5(ta, fabsf(u.x));
  ins5(tb, fabsf(w.x));
  ins5(ta, fabsf(u.y));
  ins5(tb, fabsf(w.y));
  ins5(ta, fabsf(u.z));
  ins5(tb, fabsf(w.z));
  ins5(ta, fabsf(u.w));
  ins5(tb, fabsf(w.w));
}

// 4-bit code via threshold compares: c in 0..5 (magnitude rank), +6 if neg.
__device__ inline unsigned code1t(float xv, const float (&tp)[5],
                                  const float (&tn)[5]) {
  const bool neg = xv < 0.0f;
  const float ax = fabsf(xv);
  unsigned c = neg ? 6u : 0u;
#pragma unroll
  for (int k = 0; k < 5; ++k) {
    float t = neg ? tn[k] : tp[k];
    c += (unsigned)(ax >= t);
  }
  return c;
}

__device__ inline unsigned code4t(float4 v, const float (&tp)[5],
                                  const float (&tn)[5]) {
  return code1t(v.x, tp, tn) | (code1t(v.y, tp, tn) << 4) |
         (code1t(v.z, tp, tn) << 8) | (code1t(v.w, tp, tn) << 12);
}

// Pass 1: ONE thread per 64-element quant block (r8's proven-fast geometry:
// 256 B contiguous per thread -> each wave spans 16 KB of HBM = channel
// spread; the 4-lane 256-B-stride pattern of r11/12 camped on few channels).
// Divide-free coding; codes stored as two dense SoA uint4 streams.
// NO atomics anywhere.
__global__ __launch_bounds__(256) void scales_k(const float4* __restrict__ x4,
                                                float* __restrict__ scales,
                                                float2* __restrict__ part,
                                                uint4* __restrict__ codesA,
                                                uint4* __restrict__ codesB,
                                                int nblocks) {
  __shared__ float smn[256];
  __shared__ float smx[256];
  const int t = threadIdx.x;
  const int b = blockIdx.x * 256 + t;
  float sc_min = __uint_as_float(0x7F800000u);  // +inf
  float sc_max = 0.0f;
  if (b < nblocks) {
    const float4* p = x4 + (size_t)b * (QBLOCK / 4);
    float4 a0 = p[0], a1 = p[1], a2 = p[2], a3 = p[3];
    float4 a4 = p[4], a5 = p[5], a6 = p[6], a7 = p[7];
    float4 b0 = p[8], b1 = p[9], b2 = p[10], b3 = p[11];
    float4 b4 = p[12], b5 = p[13], b6 = p[14], b7 = p[15];
    // Two interleaved top-5 lists for ILP; |x| >= 0 > -1 sentinel.
    float ta[5] = {-1.f, -1.f, -1.f, -1.f, -1.f};
    float tb[5] = {-1.f, -1.f, -1.f, -1.f, -1.f};
    ins4x(ta, tb, a0, a1);
    ins4x(ta, tb, a2, a3);
    ins4x(ta, tb, a4, a5);
    ins4x(ta, tb, a6, a7);
    ins4x(ta, tb, b0, b1);
    ins4x(ta, tb, b2, b3);
    ins4x(ta, tb, b4, b5);
    ins4x(ta, tb, b6, b7);
#pragma unroll
    for (int k = 0; k < 5; ++k) ins5(ta, tb[k]);  // top-5 of the 64
    // sorted[60] = 4th largest = ta[3]; sorted[59] = 5th largest = ta[4]
    // bit-exact jax quantile: add(mul(lo,w_lo), mul(hi,w_hi)) in f32, no FMA
    float sc = __fadd_rn(__fmul_rn(ta[4], W59), __fmul_rn(ta[3], W60));
    sc = fmaxf(sc, 1e-8f);  // jnp.clip(scales, 1e-8)
    scales[b] = sc;
    sc_min = sc;
    sc_max = sc;
    // Per-block divide-free thresholds (exact; see thr()).
    const double sd = (double)sc;
    float tp[5], tn[5];
    tp[0] = thr(sd, MP0);
    tn[0] = thr(sd, MN0);
    tp[1] = thr(sd, MP1);
    tn[1] = thr(sd, MN1);
    tp[2] = thr(sd, MP2);
    tn[2] = thr(sd, MN2);
    tp[3] = thr(sd, MP3);
    tn[3] = thr(sd, MN3);
    tp[4] = thr(sd, MP4);
    tn[4] = thr(sd, MN4);
    // Code all 64 resident elements; two dense 16-B/lane store instructions.
    uint4 w0, w1;
    w0.x = code4t(a0, tp, tn) | (code4t(a1, tp, tn) << 16);
    w0.y = code4t(a2, tp, tn) | (code4t(a3, tp, tn) << 16);
    w0.z = code4t(a4, tp, tn) | (code4t(a5, tp, tn) << 16);
    w0.w = code4t(a6, tp, tn) | (code4t(a7, tp, tn) << 16);
    w1.x = code4t(b0, tp, tn) | (code4t(b1, tp, tn) << 16);
    w1.y = code4t(b2, tp, tn) | (code4t(b3, tp, tn) << 16);
    w1.z = code4t(b4, tp, tn) | (code4t(b5, tp, tn) << 16);
    w1.w = code4t(b6, tp, tn) | (code4t(b7, tp, tn) << 16);
    codesA[b] = w0;  // codes of elements 0..31
    codesB[b] = w1;  // codes of elements 32..63
  }
  smn[t] = sc_min;
  smx[t] = sc_max;
  __syncthreads();
  if (t < 64) {
    float mn = fminf(fminf(smn[t], smn[t + 64]), fminf(smn[t + 128], smn[t + 192]));
    float mx = fmaxf(fmaxf(smx[t], smx[t + 64]), fmaxf(smx[t + 128], smx[t + 192]));
#pragma unroll
    for (int off = 32; off; off >>= 1) {
      mn = fminf(mn, __shfl_xor(mn, off));
      mx = fmaxf(mx, __shfl_xor(mx, off));
    }
    if (t == 0) part[blockIdx.x] = make_float2(mn, mx);
  }
}

// Decode one 4-bit code -> level * dq (bit-exact final multiply).
__device__ inline float dec1(unsigned code, float dq) {
  unsigned m = (code >= 6u) ? code - 6u : code;
  float mag = (m == 0u) ? 0.0f
            : (m == 1u) ? 0.75f
            : (m == 2u) ? 1.0f
            : (m == 3u) ? 1.5f
            : (m == 4u) ? 2.0f
                        : 3.0f;
  float lvl = (code >= 6u) ? -mag : mag;
  return __fmul_rn(lvl, dq);
}

// Pass 2: thread <-> output float4 index (grid-stride) => coalesced code
// loads (two compact streams) and 16-B stores.
__global__ __launch_bounds__(256) void deq_k(const ushort* __restrict__ cA,
                                             const ushort* __restrict__ cB,
                                             const float* __restrict__ scales,
                                             const float2* __restrict__ part,
                                             float4* __restrict__ o4, int n4,
                                             int nwg) {
  __shared__ float smn[256];
  __shared__ float smx[256];
  __shared__ float bc[2];
  const int t = threadIdx.x;
  float mn = __uint_as_float(0x7F800000u);
  float mx = 0.0f;
  for (int i = t; i < nwg; i += 256) {
    float2 pr = part[i];
    mn = fminf(mn, pr.x);
    mx = fmaxf(mx, pr.y);
  }
  smn[t] = mn;
  smx[t] = mx;
  __syncthreads();
  if (t < 64) {
    float mn2 = fminf(fminf(smn[t], smn[t + 64]), fminf(smn[t + 128], smn[t + 192]));
    float mx2 = fmaxf(fmaxf(smx[t], smx[t + 64]), fmaxf(smx[t + 128], smx[t + 192]));
#pragma unroll
    for (int off = 32; off; off >>= 1) {
      mn2 = fminf(mn2, __shfl_xor(mn2, off));
      mx2 = fmaxf(mx2, __shfl_xor(mx2, off));
    }
    if (t == 0) {
      bc[0] = mn2;
      bc[1] = mx2;
    }
  }
  __syncthreads();
  const float smin = bc[0];
  const float smax = bc[1];
  const bool nd = smax > smin;
  const float ss = nd ? __fdiv_rn(__fsub_rn(smax, smin), 255.0f) : 1.0f;

  int i = blockIdx.x * 256 + t;
  const int stride = gridDim.x * 256;
  for (; i < n4; i += stride) {
    const int b = i >> 4;
    const int k = i & 15;
    // Select stream A (elements 0..31) or B (32..63) arithmetically.
    const ushort* cp = (k < 8) ? (cA + (size_t)b * 8 + k)
                               : (cB + (size_t)b * 8 + (k - 8));
    unsigned w = *cp;
    float s = scales[b];
    float dq = 0.0f;
    if (nd) {
      float q = rintf(__fdiv_rn(__fsub_rn(s, smin), ss));  // jnp.round = RNE
      q = fminf(fmaxf(q, 0.0f), 255.0f);
      dq = __fmul_rn(q, ss);  // q_scales * scale_scale (no s_min added back)
    }
    float4 o;
    o.x = dec1(w & 15u, dq);
    o.y = dec1((w >> 4) & 15u, dq);
    o.z = dec1((w >> 8) & 15u, dq);
    o.w = dec1((w >> 12) & 15u, dq);
    o4[i] = o;
  }
}

}  // namespace

extern "C" void kernel_launch(void* const* d_in, const int* in_sizes, int n_in,
                              void* d_out, int out_size, void* d_ws, size_t ws_size,
                              hipStream_t stream) {
  const float* x = (const float*)d_in[0];
  float* out = (float*)d_out;
  const int n = in_sizes[0];
  const int nblocks = n / QBLOCK;
  const int nwg = (nblocks + 255) / 256;  // 1024 for 2048x8192

  // ws layout (16-B aligned): codesA | codesB | scales | partials
  uint4* codesA = (uint4*)d_ws;                                   // 16 B/block
  uint4* codesB = (uint4*)((char*)d_ws + (size_t)nblocks * 16);   // 16 B/block
  float* scales = (float*)((char*)d_ws + (size_t)nblocks * 32);   // 4 B/block
  float2* part = (float2*)((char*)scales + (size_t)nblocks * 4);

  hipLaunchKernelGGL(scales_k, dim3(nwg), dim3(256), 0, stream,
                     (const float4*)x, scales, part, codesA, codesB, nblocks);
  const int n4 = n / 4;
  hipLaunchKernelGGL(deq_k, dim3(2048), dim3(256), 0, stream,
                     (const ushort*)codesA, (const ushort*)codesB, scales, part,
                     (float4*)out, n4, nwg);
}